// Round 1
// 8874.912 us; speedup vs baseline: 1.4081x; 1.4081x over previous
//
#include <hip/hip_runtime.h>
#include <hip/hip_bf16.h>
#include <math.h>

#define BBATCH 4
#define SSEQ   2048
#define DMODEL 768
#define NHEAD  12
#define DHEAD  64
#define DFFN   3072
#define NLAYER 12
#define NEGV   (-1e9f)
#define QSCALE 0.125f
#define NQKV   3840   // 5*768: q|k|v|kg|vg interleaved per token

typedef unsigned short u16;
typedef unsigned int u32;
typedef __attribute__((ext_vector_type(8))) short bf16x8;
typedef __attribute__((ext_vector_type(4))) float f32x4;

__device__ __forceinline__ u16 f2bf(float x) {
  __hip_bfloat16 h = __float2bfloat16(x);
  union { __hip_bfloat16 h; u16 u; } c;
  c.h = h;
  return c.u;
}

__device__ __forceinline__ float bf2f(short u) {
  return __uint_as_float(((u32)(u16)u) << 16);
}

__device__ __forceinline__ void unpack8(uint4 r, float* o) {
  o[0] = __uint_as_float(r.x << 16); o[1] = __uint_as_float(r.x & 0xffff0000u);
  o[2] = __uint_as_float(r.y << 16); o[3] = __uint_as_float(r.y & 0xffff0000u);
  o[4] = __uint_as_float(r.z << 16); o[5] = __uint_as_float(r.z & 0xffff0000u);
  o[6] = __uint_as_float(r.w << 16); o[7] = __uint_as_float(r.w & 0xffff0000u);
}

__device__ __forceinline__ void load_lds16(const void* g, void* l) {
  __builtin_amdgcn_global_load_lds(
      (const __attribute__((address_space(1))) unsigned int*)g,
      (__attribute__((address_space(3))) unsigned int*)l, 16, 0, 0);
}

// ---------------- block reduction helper (256 threads) ----------------
__device__ __forceinline__ float block_sum_256(float v, float* red) {
  int t = threadIdx.x;
  red[t] = v;
  __syncthreads();
#pragma unroll
  for (int s = 128; s > 0; s >>= 1) {
    if (t < s) red[t] += red[t + s];
    __syncthreads();
  }
  float r = red[0];
  __syncthreads();
  return r;
}

// ---------------- embeddings + LN (dual write fp32 + bf16) ----------------
__global__ __launch_bounds__(256) void embed_ln_kernel(
    const int* __restrict__ ids, const float* __restrict__ ew,
    const float* __restrict__ ep, const float* __restrict__ lns,
    const float* __restrict__ lnb, float* __restrict__ h,
    u16* __restrict__ hb) {
  __shared__ float red[256];
  int tok = blockIdx.x;
  int s = tok % SSEQ;
  int id = ids[tok];
  const float* wp = ew + (size_t)id * DMODEL;
  const float* pp = ep + (size_t)s * DMODEL;
  float vals[3];
  float sum = 0.f;
#pragma unroll
  for (int i = 0; i < 3; i++) {
    int d = threadIdx.x + i * 256;
    vals[i] = wp[d] + pp[d];
    sum += vals[i];
  }
  float mean = block_sum_256(sum, red) * (1.0f / DMODEL);
  float vsum = 0.f;
#pragma unroll
  for (int i = 0; i < 3; i++) { float df = vals[i] - mean; vsum += df * df; }
  float var = block_sum_256(vsum, red) * (1.0f / DMODEL);
  float inv = rsqrtf(var + 1e-5f);
#pragma unroll
  for (int i = 0; i < 3; i++) {
    int d = threadIdx.x + i * 256;
    float o = (vals[i] - mean) * inv * lns[d] + lnb[d];
    h[(size_t)tok * DMODEL + d] = o;
    hb[(size_t)tok * DMODEL + d] = f2bf(o);
  }
}

// ---------------- h = LN(h + delta), dual write ----------------
__global__ __launch_bounds__(256) void add_ln_kernel(
    float* __restrict__ h, const float* __restrict__ delta,
    const float* __restrict__ lns, const float* __restrict__ lnb,
    u16* __restrict__ hb) {
  __shared__ float red[256];
  size_t base = (size_t)blockIdx.x * DMODEL;
  float vals[3];
  float sum = 0.f;
#pragma unroll
  for (int i = 0; i < 3; i++) {
    int d = threadIdx.x + i * 256;
    vals[i] = h[base + d] + delta[base + d];
    sum += vals[i];
  }
  float mean = block_sum_256(sum, red) * (1.0f / DMODEL);
  float vsum = 0.f;
#pragma unroll
  for (int i = 0; i < 3; i++) { float df = vals[i] - mean; vsum += df * df; }
  float var = block_sum_256(vsum, red) * (1.0f / DMODEL);
  float inv = rsqrtf(var + 1e-5f);
#pragma unroll
  for (int i = 0; i < 3; i++) {
    int d = threadIdx.x + i * 256;
    float o = (vals[i] - mean) * inv * lns[d] + lnb[d];
    h[base + d] = o;
    hb[base + d] = f2bf(o);
  }
}

// ---------------- transpose+convert 64x64 tile body ----------------
__device__ __forceinline__ void convt_tile(const float* __restrict__ W,
                                           u16* __restrict__ Wt, int K, int N) {
  __shared__ float tl[64][65];
  int k0 = blockIdx.x * 64, n0 = blockIdx.y * 64;
  int t = threadIdx.x;
  int l16 = t & 15, rg = t >> 4;
#pragma unroll
  for (int i = 0; i < 4; i++) {
    int r = rg + i * 16;
    float4 vv = *(const float4*)(W + (size_t)(k0 + r) * N + n0 + l16 * 4);
    tl[r][l16 * 4 + 0] = vv.x;
    tl[r][l16 * 4 + 1] = vv.y;
    tl[r][l16 * 4 + 2] = vv.z;
    tl[r][l16 * 4 + 3] = vv.w;
  }
  __syncthreads();
#pragma unroll
  for (int i = 0; i < 4; i++) {
    int nrow = rg + i * 16;
    ushort4 o;
    o.x = f2bf(tl[l16 * 4 + 0][nrow]);
    o.y = f2bf(tl[l16 * 4 + 1][nrow]);
    o.z = f2bf(tl[l16 * 4 + 2][nrow]);
    o.w = f2bf(tl[l16 * 4 + 3][nrow]);
    *(ushort4*)(Wt + (size_t)(n0 + nrow) * K + k0 + l16 * 4) = o;
  }
}

// generic convt (Wi / Wf)
__global__ __launch_bounds__(256) void convt_kernel(
    const float* __restrict__ W, u16* __restrict__ Wt, int K, int N) {
  convt_tile(W, Wt, K, N);
}

// fused convt of six DxD matrices (q,k,v,kg,vg,wo) via blockIdx.z
__global__ __launch_bounds__(256) void convt6_kernel(
    const float* __restrict__ W0, const float* __restrict__ W1,
    const float* __restrict__ W2, const float* __restrict__ W3,
    const float* __restrict__ W4, const float* __restrict__ W5,
    u16* __restrict__ out) {
  int z = blockIdx.z;
  const float* W = (z == 0) ? W0 : (z == 1) ? W1 : (z == 2) ? W2
                 : (z == 3) ? W3 : (z == 4) ? W4 : W5;
  convt_tile(W, out + (size_t)z * DMODEL * DMODEL, DMODEL, DMODEL);
}

// concat per-layer biases bq|bk|bv|bkg|bvg -> fb[L][NQKV] (run once)
__global__ __launch_bounds__(256) void bias_cat_kernel(
    const float* __restrict__ bq, const float* __restrict__ bk,
    const float* __restrict__ bv, const float* __restrict__ bkg,
    const float* __restrict__ bvg, float* __restrict__ fb) {
  int idx = blockIdx.x * 256 + threadIdx.x;
  if (idx >= NLAYER * NQKV) return;
  int l = idx / NQKV, j = idx % NQKV;
  float v;
  if (j < 768)       v = bq[l * DMODEL + j];
  else if (j < 1536) v = bk[l * DMODEL + j - 768];
  else if (j < 2304) v = bv[l * DMODEL + j - 1536];
  else if (j < 3072) v = bkg[l * DMODEL + j - 2304];
  else               v = bvg[l * DMODEL + j - 3072];
  fb[idx] = v;
}

// ---------------- bf16 MFMA GEMM (m97 structure): C = A[M,K] @ Bt[N,K]^T + bias ----
// EPI: 0 = bias -> fp32 out; 1 = bias+gelu -> bf16 out;
// EPI: 2 = bias -> bf16 out, with V columns [1536,2304) redirected TRANSPOSED
//          into VtOut[b][h][d][s] (head-transposed V panel for local attention).
template <int EPI>
__global__ __launch_bounds__(256) void mfma_gemm_kernel(
    const u16* __restrict__ A, const u16* __restrict__ Bt,
    const float* __restrict__ bias, float* __restrict__ Cf,
    u16* __restrict__ Cb, u16* __restrict__ VtOut, int M, int N, int K) {
  __shared__ u16 As[128 * 32];
  __shared__ u16 Bs[128 * 32];
  int t = threadIdx.x;
  int lane = t & 63;
  int w = t >> 6;
  int m0 = blockIdx.x * 128, n0 = blockIdx.y * 128;
  int wm = (w >> 1) * 64, wn = (w & 1) * 64;

  f32x4 acc[4][4];
#pragma unroll
  for (int i = 0; i < 4; i++)
#pragma unroll
    for (int j = 0; j < 4; j++) acc[i][j] = (f32x4){0.f, 0.f, 0.f, 0.f};

  int rA = lane >> 2;
  int kseg = (lane & 3) * 8;
  const u16* gA0 = A + (size_t)(m0 + 2 * w * 16 + rA) * K + kseg;
  const u16* gB0 = Bt + (size_t)(n0 + 2 * w * 16 + rA) * K + kseg;
  char* lA0 = (char*)As + (2 * w) * 1024;
  char* lB0 = (char*)Bs + (2 * w) * 1024;

  const u16* fA = As + (wm + (lane & 15)) * 32 + (lane >> 4) * 8;
  const u16* fB = Bs + (wn + (lane & 15)) * 32 + (lane >> 4) * 8;

  for (int k0 = 0; k0 < K; k0 += 32) {
    load_lds16(gA0 + k0, lA0);
    load_lds16(gA0 + (size_t)16 * K + k0, lA0 + 1024);
    load_lds16(gB0 + k0, lB0);
    load_lds16(gB0 + (size_t)16 * K + k0, lB0 + 1024);
    __syncthreads();
    bf16x8 fa[4], fb[4];
#pragma unroll
    for (int i = 0; i < 4; i++) {
      fa[i] = *(const bf16x8*)(fA + i * 16 * 32);
      fb[i] = *(const bf16x8*)(fB + i * 16 * 32);
    }
#pragma unroll
    for (int mi = 0; mi < 4; mi++)
#pragma unroll
      for (int ni = 0; ni < 4; ni++)
        acc[mi][ni] = __builtin_amdgcn_mfma_f32_16x16x32_bf16(
            fa[mi], fb[ni], acc[mi][ni], 0, 0, 0);
    __syncthreads();
  }

  int col0 = n0 + wn + (lane & 15);
  int row0 = m0 + wm + (lane >> 4) * 4;
#pragma unroll
  for (int mi = 0; mi < 4; mi++)
#pragma unroll
    for (int ni = 0; ni < 4; ni++) {
      int ncol = col0 + ni * 16;
      float bvv = bias[ncol];
      if (EPI == 2 && ncol >= 1536 && ncol < 2304) {
        // V head panel, transposed: vT[((bb*12+hh)*64+dd)*2048 + s]
        int dcol = ncol - 1536;
        int h2 = dcol >> 6, dd = dcol & 63;
        int row0m = row0 + mi * 16;
        int bb2 = row0m >> 11, ss = row0m & 2047;
        ushort4 pk;
        pk.x = f2bf(acc[mi][ni][0] + bvv);
        pk.y = f2bf(acc[mi][ni][1] + bvv);
        pk.z = f2bf(acc[mi][ni][2] + bvv);
        pk.w = f2bf(acc[mi][ni][3] + bvv);
        *(ushort4*)(VtOut + (((size_t)(bb2 * NHEAD + h2)) * DHEAD + dd) * SSEQ + ss) = pk;
      } else {
#pragma unroll
        for (int r = 0; r < 4; r++) {
          int mrow = row0 + mi * 16 + r;
          float vv = acc[mi][ni][r] + bvv;
          if (EPI == 0) {
            Cf[(size_t)mrow * N + ncol] = vv;
          } else if (EPI == 1) {
            vv = 0.5f * vv * (1.f + erff(vv * 0.70710678118654752f));
            Cb[(size_t)mrow * N + ncol] = f2bf(vv);
          } else {
            Cb[(size_t)mrow * N + ncol] = f2bf(vv);
          }
        }
      }
    }
}

// ---------------- local (banded) attention, MFMA flash-style ----------------
// Block = 64 queries of one (b,h); 4 waves x 16 q-rows. 9 KV tiles of 64 keys.
// Swapped QK^T (S^T = K @ Q^T) so softmax state is lane-local; PV via
// OT = mfma(V^T, P) with V^T staged from the vT panel the QKV GEMM produced.
// K/V^T rows are 128B -> XOR-swizzle 16B segments via pre-swizzled global src.
// grid = B*H*32 = 1536 (bijective XCD swizzle: 1536 % 8 == 0).
__global__ __launch_bounds__(256) void local_attn_kernel(
    const u16* __restrict__ qkv, const u16* __restrict__ vT,
    const float* __restrict__ amask, u16* __restrict__ Ob) {
  int x = blockIdx.x;
  int lid = (x & 7) * 192 + (x >> 3);      // XCD-contiguous chunks
  int ck = lid & 31;
  int hh = (lid >> 5) % NHEAD;
  int bb = lid / (32 * NHEAD);
  int q0 = ck * 64;

  __shared__ __align__(16) u16 Ks[64 * 64];   // [key][dim], segs ^ (key&7)
  __shared__ __align__(16) u16 Vs[64 * 64];   // [dim][key], segs ^ (dim&7)
  __shared__ __align__(16) u16 Pl[4][16 * 72];
  __shared__ float sm[64];
  __shared__ float k0s[64], v0s[64];

  int t = threadIdx.x;
  int l = t & 63;
  int w = t >> 6;
  int lq = l & 15;   // q (n index)
  int g  = l >> 4;   // 4-lane group

  // one-time: token-0 K and V columns (joint-softmax global key)
  if (t < 128) {
    int d = t & 63;
    if (t < 64) {
      u16 kv = qkv[((size_t)bb * SSEQ) * NQKV + 768 + hh * DHEAD + d];
      k0s[d] = __uint_as_float(((u32)kv) << 16);
    } else {
      u16 vv = vT[(((size_t)(bb * NHEAD + hh)) * DHEAD + d) * SSEQ];
      v0s[d] = __uint_as_float(((u32)vv) << 16);
    }
  }

  // Q B-fragments direct from global (per-lane 16B, held for whole kernel)
  int qtok = q0 + w * 16 + lq;
  const u16* qp = qkv + ((size_t)(bb * SSEQ + qtok)) * NQKV + hh * DHEAD + g * 8;
  bf16x8 qf0 = *(const bf16x8*)(qp);        // dims g*8..+7
  bf16x8 qf1 = *(const bf16x8*)(qp + 32);   // dims 32+g*8..+7

  // staging geometry: inst i covers rows (i*32 + w*8 + (l>>3)), phys seg l&7
  int srow = w * 8 + (l >> 3);
  int lseg = (l & 7) ^ (srow & 7);          // same for srow and srow+32
  const u16* kbase = qkv + ((size_t)bb * SSEQ) * NQKV + 768 + hh * DHEAD + lseg * 8;
  const u16* vbase = vT + (((size_t)(bb * NHEAD + hh)) * DHEAD + srow) * SSEQ + lseg * 8;
  char* ldK0 = (char*)Ks + w * 1024;
  char* ldK1 = (char*)Ks + 4096 + w * 1024;
  char* ldV0 = (char*)Vs + w * 1024;
  char* ldV1 = (char*)Vs + 4096 + w * 1024;

  float mrun = -INFINITY, lrun = 0.f;
  f32x4 ot[4];
#pragma unroll
  for (int ti = 0; ti < 4; ti++) ot[ti] = (f32x4){0.f, 0.f, 0.f, 0.f};

  u16* pw = &Pl[w][0];

  for (int tt = 0; tt < 9; tt++) {
    int jp0 = q0 - 256 + tt * 64;           // 64-aligned, so never partial
    if (jp0 < 0 || jp0 >= SSEQ) continue;

    load_lds16(kbase + (size_t)(jp0 + srow) * NQKV, ldK0);
    load_lds16(kbase + (size_t)(jp0 + srow + 32) * NQKV, ldK1);
    load_lds16(vbase + jp0, ldV0);
    load_lds16(vbase + (size_t)32 * SSEQ + jp0, ldV1);
    if (t < 64) sm[t] = amask[bb * SSEQ + jp0 + t];
    __syncthreads();

    // S^T = K @ Q^T : 4 key-tiles x (K=64 -> 2 mfma)
    f32x4 st[4];
#pragma unroll
    for (int ti = 0; ti < 4; ti++) {
      st[ti] = (f32x4){0.f, 0.f, 0.f, 0.f};
      int krow = ti * 16 + lq;
      const u16* kr = Ks + krow * 64;
      bf16x8 kf0 = *(const bf16x8*)(kr + ((0 + g) ^ (krow & 7)) * 8);
      bf16x8 kf1 = *(const bf16x8*)(kr + ((4 + g) ^ (krow & 7)) * 8);
      st[ti] = __builtin_amdgcn_mfma_f32_16x16x32_bf16(kf0, qf0, st[ti], 0, 0, 0);
      st[ti] = __builtin_amdgcn_mfma_f32_16x16x32_bf16(kf1, qf1, st[ti], 0, 0, 0);
    }

    // mask + online softmax (lane holds q = lq, keys ti*16 + g*4 + r)
    float mx = -INFINITY;
#pragma unroll
    for (int ti = 0; ti < 4; ti++)
#pragma unroll
      for (int r = 0; r < 4; r++) {
        int kk = ti * 16 + g * 4 + r;
        int jp = jp0 + kk;
        int rel = jp - qtok;
        bool ok = (jp != 0) && (rel <= 256) && (rel >= -256) && (sm[kk] > 0.5f);
        float s = ok ? st[ti][r] * QSCALE : NEGV;
        st[ti][r] = s;
        mx = fmaxf(mx, s);
      }
    mx = fmaxf(mx, __shfl_xor(mx, 16, 64));
    mx = fmaxf(mx, __shfl_xor(mx, 32, 64));
    float mnew = fmaxf(mrun, mx);
    float cr = expf(mrun - mnew);
    float ssum = 0.f;
#pragma unroll
    for (int ti = 0; ti < 4; ti++) {
      float e0 = expf(st[ti][0] - mnew);
      float e1 = expf(st[ti][1] - mnew);
      float e2 = expf(st[ti][2] - mnew);
      float e3 = expf(st[ti][3] - mnew);
      ssum += (e0 + e1) + (e2 + e3);
      ushort4 pk;
      pk.x = f2bf(e0); pk.y = f2bf(e1); pk.z = f2bf(e2); pk.w = f2bf(e3);
      *(ushort4*)(pw + lq * 72 + ti * 16 + g * 4) = pk;   // P[q][k], pitch 72
    }
    ssum += __shfl_xor(ssum, 16, 64);
    ssum += __shfl_xor(ssum, 32, 64);
    lrun = lrun * cr + ssum;
    mrun = mnew;

    // rescale running output (per-lane: all ot share this lane's q)
#pragma unroll
    for (int ti = 0; ti < 4; ti++) {
      ot[ti][0] *= cr; ot[ti][1] *= cr; ot[ti][2] *= cr; ot[ti][3] *= cr;
    }

    // OT += V^T @ P^T : A = Vs[d][k] (4 d-tiles), B = P[q][k]
    bf16x8 pf0 = *(const bf16x8*)(pw + lq * 72 + g * 8);
    bf16x8 pf1 = *(const bf16x8*)(pw + lq * 72 + 32 + g * 8);
#pragma unroll
    for (int ti = 0; ti < 4; ti++) {
      int drow = ti * 16 + lq;
      const u16* vr = Vs + drow * 64;
      bf16x8 vf0 = *(const bf16x8*)(vr + ((0 + g) ^ (drow & 7)) * 8);
      bf16x8 vf1 = *(const bf16x8*)(vr + ((4 + g) ^ (drow & 7)) * 8);
      ot[ti] = __builtin_amdgcn_mfma_f32_16x16x32_bf16(vf0, pf0, ot[ti], 0, 0, 0);
      ot[ti] = __builtin_amdgcn_mfma_f32_16x16x32_bf16(vf1, pf1, ot[ti], 0, 0, 0);
    }
    __syncthreads();
  }

  // token-0 global key column (joint softmax, never masked)
  float gs = 0.f;
#pragma unroll
  for (int j = 0; j < 8; j++) {
    gs = fmaf(bf2f(qf0[j]), k0s[g * 8 + j], gs);
    gs = fmaf(bf2f(qf1[j]), k0s[32 + g * 8 + j], gs);
  }
  gs += __shfl_xor(gs, 16, 64);
  gs += __shfl_xor(gs, 32, 64);
  float gsc = gs * QSCALE;
  float mnew = fmaxf(mrun, gsc);
  float cr = expf(mrun - mnew);
  float p0 = expf(gsc - mnew);
  float linv = 1.0f / (lrun * cr + p0);

  // finalize -> per-wave LDS stage (reuse Pl) -> coalesced bf16 store
#pragma unroll
  for (int ti = 0; ti < 4; ti++) {
    int d = ti * 16 + g * 4;
    ushort4 ov;
    ov.x = f2bf((ot[ti][0] * cr + p0 * v0s[d + 0]) * linv);
    ov.y = f2bf((ot[ti][1] * cr + p0 * v0s[d + 1]) * linv);
    ov.z = f2bf((ot[ti][2] * cr + p0 * v0s[d + 2]) * linv);
    ov.w = f2bf((ot[ti][3] * cr + p0 * v0s[d + 3]) * linv);
    *(ushort4*)(pw + lq * 72 + d) = ov;
  }
  int qq = l >> 2, s4 = l & 3;
  uint4 o0 = *(const uint4*)(pw + qq * 72 + s4 * 8);
  uint4 o1 = *(const uint4*)(pw + qq * 72 + 32 + s4 * 8);
  size_t ob = ((size_t)(bb * SSEQ + q0 + w * 16 + qq)) * DMODEL + hh * DHEAD + s4 * 8;
  *(uint4*)(Ob + ob) = o0;
  *(uint4*)(Ob + ob + 32) = o1;
}

// ---------------- global token-0 query attention (bf16 kg/vg): grid = B*H ------
__global__ __launch_bounds__(256) void global_attn_kernel(
    const float* __restrict__ qg, const u16* __restrict__ qkv,
    const float* __restrict__ amask, u16* __restrict__ Ob) {
  int bb = blockIdx.x / NHEAD;
  int hh = blockIdx.x % NHEAD;
  __shared__ float p[SSEQ];
  __shared__ float qv[64];
  __shared__ float red[256];
  __shared__ float part[4][64];
  int t = threadIdx.x;
  if (t < 64) qv[t] = qg[(bb * NHEAD + hh) * 64 + t];
  __syncthreads();
  float mx = -INFINITY;
#pragma unroll
  for (int i = 0; i < 8; i++) {
    int s = t + i * 256;
    const u16* kp = qkv + ((size_t)(bb * SSEQ + s)) * NQKV + 2304 + hh * DHEAD;
    float acc = 0.f;
#pragma unroll
    for (int d8 = 0; d8 < 8; d8++) {
      float f8[8];
      unpack8(*(const uint4*)(kp + d8 * 8), f8);
#pragma unroll
      for (int u = 0; u < 8; u++) acc = fmaf(qv[d8 * 8 + u], f8[u], acc);
    }
    if (!(amask[bb * SSEQ + s] > 0.5f)) acc = NEGV;
    p[s] = acc;
    mx = fmaxf(mx, acc);
  }
  red[t] = mx;
  __syncthreads();
  for (int sft = 128; sft > 0; sft >>= 1) {
    if (t < sft) red[t] = fmaxf(red[t], red[t + sft]);
    __syncthreads();
  }
  mx = red[0];
  __syncthreads();
  float lsum = 0.f;
#pragma unroll
  for (int i = 0; i < 8; i++) {
    int s = t + i * 256;
    float e = expf(p[s] - mx);
    p[s] = e;
    lsum += e;
  }
  float l = block_sum_256(lsum, red);
  int d = t & 63, stripe = t >> 6;
  float acc = 0.f;
  for (int s = stripe * 512; s < stripe * 512 + 512; s++) {
    u16 vv = qkv[((size_t)(bb * SSEQ + s)) * NQKV + 3072 + hh * DHEAD + d];
    acc = fmaf(p[s], __uint_as_float(((u32)vv) << 16), acc);
  }
  part[stripe][d] = acc;
  __syncthreads();
  if (t < 64) {
    float sum = part[0][t] + part[1][t] + part[2][t] + part[3][t];
    Ob[((size_t)(bb * SSEQ)) * DMODEL + hh * DHEAD + t] = f2bf(sum / l);
  }
}

// ---------------- tiny row-vector x matrix (fp32) ----------------
__global__ __launch_bounds__(256) void rowvec_mat_kernel(
    const float* __restrict__ x, size_t xstride, const float* __restrict__ Wt,
    const float* __restrict__ bias, float* __restrict__ y, int K, int N,
    float scl, int act) {
  int ncg = N >> 8;
  int bb = blockIdx.x / ncg;
  int cg = blockIdx.x % ncg;
  int j = cg * 256 + threadIdx.x;
  const float* xr = x + (size_t)bb * xstride;
  float acc = bias[j];
  for (int kk = 0; kk < K; kk++) acc = fmaf(xr[kk], Wt[(size_t)kk * N + j], acc);
  acc *= scl;
  if (act == 1) acc = tanhf(acc);
  y[(size_t)bb * N + j] = acc;
}

// ---------------- final head ----------------
__global__ __launch_bounds__(256) void head_kernel(
    const float* __restrict__ pooled, const float* __restrict__ clsW,
    const float* __restrict__ clsb, const float* __restrict__ mcW,
    const float* __restrict__ mcb, float* __restrict__ out) {
  __shared__ float lg[8];
  __shared__ float o16[16];
  int t = threadIdx.x;
  if (t < 8) {
    int bb = t >> 1, cc2 = t & 1;
    float acc = clsb[cc2];
    for (int kk = 0; kk < DMODEL; kk++)
      acc = fmaf(pooled[bb * DMODEL + kk], clsW[kk * 2 + cc2], acc);
    lg[t] = acc;
  }
  __syncthreads();
  if (t < 16) {
    float acc = mcb[t];
    for (int i = 0; i < 8; i++) acc = fmaf(lg[i], mcW[i * 16 + t], acc);
    o16[t] = acc;
  }
  __syncthreads();
  if (t == 0) {
    float mx = o16[0];
    for (int i = 1; i < 16; i++) mx = fmaxf(mx, o16[i]);
    float sum = 0.f;
    float e[16];
    for (int i = 0; i < 16; i++) { e[i] = expf(o16[i] - mx); sum += e[i]; }
    for (int i = 0; i < 16; i++) out[i] = e[i] / sum;
  }
}

// ---------------- host launcher ----------------
extern "C" void kernel_launch(void* const* d_in, const int* in_sizes, int n_in,
                              void* d_out, int out_size, void* d_ws, size_t ws_size,
                              hipStream_t stream) {
  (void)in_sizes; (void)n_in; (void)out_size; (void)ws_size;
  const int*   ids      = (const int*)d_in[0];
  const float* amask    = (const float*)d_in[1];
  const float* emb_word = (const float*)d_in[2];
  const float* emb_pos  = (const float*)d_in[3];
  const float* ln_emb_s = (const float*)d_in[4];
  const float* ln_emb_b = (const float*)d_in[5];
  const float* Wq  = (const float*)d_in[6];
  const float* Wk  = (const float*)d_in[7];
  const float* Wv  = (const float*)d_in[8];
  const float* Wqg = (const float*)d_in[9];
  const float* Wkg = (const float*)d_in[10];
  const float* Wvg = (const float*)d_in[11];
  const float* Wo  = (const float*)d_in[12];
  const float* bq  = (const float*)d_in[13];
  const float* bk  = (const float*)d_in[14];
  const float* bv  = (const float*)d_in[15];
  const float* bqg = (const float*)d_in[16];
  const float* bkg = (const float*)d_in[17];
  const float* bvg = (const float*)d_in[18];
  const float* bo  = (const float*)d_in[19];
  const float* ln1_s = (const float*)d_in[20];
  const float* ln1_b = (const float*)d_in[21];
  const float* Wi  = (const float*)d_in[22];
  const float* bi  = (const float*)d_in[23];
  const float* Wf  = (const float*)d_in[24];
  const float* bf_ = (const float*)d_in[25];
  const float* ln2_s = (const float*)d_in[26];
  const float* ln2_b = (const float*)d_in[27];
  const float* pooler_W = (const float*)d_in[28];
  const float* pooler_b = (const float*)d_in[29];
  const float* cls_W = (const float*)d_in[30];
  const float* cls_b = (const float*)d_in[31];
  const float* mc_W  = (const float*)d_in[32];
  const float* mc_b  = (const float*)d_in[33];
  float* out = (float*)d_out;

  float* ws = (float*)d_ws;
  const size_t NT = (size_t)BBATCH * SSEQ;     // 8192 tokens
  const size_t TD = NT * DMODEL;               // 6.29M
  const size_t WDD = (size_t)DMODEL * DMODEL;  // 589824

  float* h  = ws;                    // [NT, D] fp32
  float* Pc = ws + TD;               // fp32 GEMM-out panel
  u16*  ub  = (u16*)(ws + 2 * TD);
  u16* hb   = ub;                    // [NT, D] bf16
  u16* attb = ub + TD;               // [NT, D] bf16
  u16* qkvb = ub + 2 * TD;           // [NT, NQKV] bf16  (5*TD)
  u16* midb = ub + 7 * TD;           // [NT, DFF] bf16   (4*TD)
  u16* vt   = midb;                  // [B,H,64,S] bf16 V^T panel (aliases midb:
                                     //  live QKV-GEMM..local_attn, dead by FFN1)
  u16* wt   = ub + 11 * TD;          // per-layer weights: 14*WDD u16
  u16* wqkvT = wt;                   // [NQKV, D]
  u16* woT   = wt + 5 * WDD;         // [D, D]
  u16* wiT   = wt + 6 * WDD;         // [DFF, D] (4 WDD)
  u16* wfT   = wt + 10 * WDD;        // [D, DFF] (4 WDD)
  float* fbias  = (float*)(wt + 14 * WDD);       // [L, NQKV]
  float* qgb    = fbias + NLAYER * NQKV;         // [B, D]
  float* pooled = qgb + BBATCH * DMODEL;         // [B, D]

  embed_ln_kernel<<<(int)NT, 256, 0, stream>>>(ids, emb_word, emb_pos,
                                               ln_emb_s, ln_emb_b, h, hb);
  bias_cat_kernel<<<(NLAYER * NQKV + 255) / 256, 256, 0, stream>>>(bq, bk, bv, bkg, bvg, fbias);

  dim3 gQKV(NT / 128, NQKV / 128);     // (64, 30)
  dim3 gDD(NT / 128, DMODEL / 128);    // (64, 6)
  dim3 gF1(NT / 128, DFFN / 128);      // (64, 24)
  dim3 c6(DMODEL / 64, DMODEL / 64, 6);
  dim3 cWi(DMODEL / 64, DFFN / 64);    // (12, 48)
  dim3 cWf(DFFN / 64, DMODEL / 64);    // (48, 12)

  for (int l = 0; l < NLAYER; l++) {
    const size_t wd = (size_t)l * WDD;
    convt6_kernel<<<c6, 256, 0, stream>>>(Wq + wd, Wk + wd, Wv + wd,
                                          Wkg + wd, Wvg + wd, Wo + wd, wt);
    convt_kernel<<<cWi, 256, 0, stream>>>(Wi + (size_t)l * DMODEL * DFFN, wiT, DMODEL, DFFN);
    convt_kernel<<<cWf, 256, 0, stream>>>(Wf + (size_t)l * DMODEL * DFFN, wfT, DFFN, DMODEL);

    // fused q|k|v|kg|vg projection -> bf16 panel (+ head-transposed V panel)
    mfma_gemm_kernel<2><<<gQKV, 256, 0, stream>>>(hb, wqkvT, fbias + (size_t)l * NQKV,
                                                  (float*)nullptr, qkvb, vt,
                                                  (int)NT, NQKV, DMODEL);
    local_attn_kernel<<<BBATCH * NHEAD * 32, 256, 0, stream>>>(qkvb, vt, amask, attb);
    rowvec_mat_kernel<<<BBATCH * 3, 256, 0, stream>>>(h, (size_t)SSEQ * DMODEL,
        Wqg + wd, bqg + l * DMODEL, qgb, DMODEL, DMODEL, QSCALE, 0);
    global_attn_kernel<<<BBATCH * NHEAD, 256, 0, stream>>>(qgb, qkvb, amask, attb);
    // output projection + residual LN
    mfma_gemm_kernel<0><<<gDD, 256, 0, stream>>>(attb, woT, bo + l * DMODEL, Pc,
                                                 (u16*)nullptr, (u16*)nullptr,
                                                 (int)NT, DMODEL, DMODEL);
    add_ln_kernel<<<(int)NT, 256, 0, stream>>>(h, Pc, ln1_s + l * DMODEL, ln1_b + l * DMODEL, hb);
    // FFN
    mfma_gemm_kernel<1><<<gF1, 256, 0, stream>>>(hb, wiT, bi + l * DFFN,
                                                 (float*)nullptr, midb, (u16*)nullptr,
                                                 (int)NT, DFFN, DMODEL);
    mfma_gemm_kernel<0><<<gDD, 256, 0, stream>>>(midb, wfT, bf_ + l * DMODEL, Pc,
                                                 (u16*)nullptr, (u16*)nullptr,
                                                 (int)NT, DMODEL, DFFN);
    add_ln_kernel<<<(int)NT, 256, 0, stream>>>(h, Pc, ln2_s + l * DMODEL, ln2_b + l * DMODEL, hb);
  }

  rowvec_mat_kernel<<<BBATCH * 3, 256, 0, stream>>>(h, (size_t)SSEQ * DMODEL,
      pooler_W, pooler_b, pooled, DMODEL, DMODEL, 1.0f, 1);
  head_kernel<<<1, 256, 0, stream>>>(pooled, cls_W, cls_b, mc_W, mc_b, out);
}

// Round 2
// 5516.926 us; speedup vs baseline: 2.2651x; 1.6087x over previous
//
#include <hip/hip_runtime.h>
#include <hip/hip_bf16.h>
#include <math.h>

#define BBATCH 4
#define SSEQ   2048
#define DMODEL 768
#define NHEAD  12
#define DHEAD  64
#define DFFN   3072
#define NLAYER 12
#define NEGV   (-1e9f)
#define QSCALE 0.125f
#define NQKV   3840   // 5*768: q|k|v|kg|vg interleaved per token

typedef unsigned short u16;
typedef unsigned int u32;
typedef __attribute__((ext_vector_type(8))) short bf16x8;
typedef __attribute__((ext_vector_type(4))) float f32x4;

__device__ __forceinline__ u16 f2bf(float x) {
  __hip_bfloat16 h = __float2bfloat16(x);
  union { __hip_bfloat16 h; u16 u; } c;
  c.h = h;
  return c.u;
}

__device__ __forceinline__ float bf2f(short u) {
  return __uint_as_float(((u32)(u16)u) << 16);
}

__device__ __forceinline__ void unpack8(uint4 r, float* o) {
  o[0] = __uint_as_float(r.x << 16); o[1] = __uint_as_float(r.x & 0xffff0000u);
  o[2] = __uint_as_float(r.y << 16); o[3] = __uint_as_float(r.y & 0xffff0000u);
  o[4] = __uint_as_float(r.z << 16); o[5] = __uint_as_float(r.z & 0xffff0000u);
  o[6] = __uint_as_float(r.w << 16); o[7] = __uint_as_float(r.w & 0xffff0000u);
}

__device__ __forceinline__ void load_lds16(const void* g, void* l) {
  __builtin_amdgcn_global_load_lds(
      (const __attribute__((address_space(1))) unsigned int*)g,
      (__attribute__((address_space(3))) unsigned int*)l, 16, 0, 0);
}

// ---------------- block reduction helper (256 threads) ----------------
__device__ __forceinline__ float block_sum_256(float v, float* red) {
  int t = threadIdx.x;
  red[t] = v;
  __syncthreads();
#pragma unroll
  for (int s = 128; s > 0; s >>= 1) {
    if (t < s) red[t] += red[t + s];
    __syncthreads();
  }
  float r = red[0];
  __syncthreads();
  return r;
}

// ---------------- embeddings + LN (dual write fp32 + bf16) ----------------
__global__ __launch_bounds__(256) void embed_ln_kernel(
    const int* __restrict__ ids, const float* __restrict__ ew,
    const float* __restrict__ ep, const float* __restrict__ lns,
    const float* __restrict__ lnb, float* __restrict__ h,
    u16* __restrict__ hb) {
  __shared__ float red[256];
  int tok = blockIdx.x;
  int s = tok % SSEQ;
  int id = ids[tok];
  const float* wp = ew + (size_t)id * DMODEL;
  const float* pp = ep + (size_t)s * DMODEL;
  float vals[3];
  float sum = 0.f;
#pragma unroll
  for (int i = 0; i < 3; i++) {
    int d = threadIdx.x + i * 256;
    vals[i] = wp[d] + pp[d];
    sum += vals[i];
  }
  float mean = block_sum_256(sum, red) * (1.0f / DMODEL);
  float vsum = 0.f;
#pragma unroll
  for (int i = 0; i < 3; i++) { float df = vals[i] - mean; vsum += df * df; }
  float var = block_sum_256(vsum, red) * (1.0f / DMODEL);
  float inv = rsqrtf(var + 1e-5f);
#pragma unroll
  for (int i = 0; i < 3; i++) {
    int d = threadIdx.x + i * 256;
    float o = (vals[i] - mean) * inv * lns[d] + lnb[d];
    h[(size_t)tok * DMODEL + d] = o;
    hb[(size_t)tok * DMODEL + d] = f2bf(o);
  }
}

// ---------------- h = LN(h + delta), dual write ----------------
__global__ __launch_bounds__(256) void add_ln_kernel(
    float* __restrict__ h, const float* __restrict__ delta,
    const float* __restrict__ lns, const float* __restrict__ lnb,
    u16* __restrict__ hb) {
  __shared__ float red[256];
  size_t base = (size_t)blockIdx.x * DMODEL;
  float vals[3];
  float sum = 0.f;
#pragma unroll
  for (int i = 0; i < 3; i++) {
    int d = threadIdx.x + i * 256;
    vals[i] = h[base + d] + delta[base + d];
    sum += vals[i];
  }
  float mean = block_sum_256(sum, red) * (1.0f / DMODEL);
  float vsum = 0.f;
#pragma unroll
  for (int i = 0; i < 3; i++) { float df = vals[i] - mean; vsum += df * df; }
  float var = block_sum_256(vsum, red) * (1.0f / DMODEL);
  float inv = rsqrtf(var + 1e-5f);
#pragma unroll
  for (int i = 0; i < 3; i++) {
    int d = threadIdx.x + i * 256;
    float o = (vals[i] - mean) * inv * lns[d] + lnb[d];
    h[base + d] = o;
    hb[base + d] = f2bf(o);
  }
}

// ---------------- transpose+convert 64x64 tile body ----------------
__device__ __forceinline__ void convt_tile(const float* __restrict__ W,
                                           u16* __restrict__ Wt, int K, int N) {
  __shared__ float tl[64][65];
  int k0 = blockIdx.x * 64, n0 = blockIdx.y * 64;
  int t = threadIdx.x;
  int l16 = t & 15, rg = t >> 4;
#pragma unroll
  for (int i = 0; i < 4; i++) {
    int r = rg + i * 16;
    float4 vv = *(const float4*)(W + (size_t)(k0 + r) * N + n0 + l16 * 4);
    tl[r][l16 * 4 + 0] = vv.x;
    tl[r][l16 * 4 + 1] = vv.y;
    tl[r][l16 * 4 + 2] = vv.z;
    tl[r][l16 * 4 + 3] = vv.w;
  }
  __syncthreads();
#pragma unroll
  for (int i = 0; i < 4; i++) {
    int nrow = rg + i * 16;
    ushort4 o;
    o.x = f2bf(tl[l16 * 4 + 0][nrow]);
    o.y = f2bf(tl[l16 * 4 + 1][nrow]);
    o.z = f2bf(tl[l16 * 4 + 2][nrow]);
    o.w = f2bf(tl[l16 * 4 + 3][nrow]);
    *(ushort4*)(Wt + (size_t)(n0 + nrow) * K + k0 + l16 * 4) = o;
  }
}

// generic convt (Wi / Wf)
__global__ __launch_bounds__(256) void convt_kernel(
    const float* __restrict__ W, u16* __restrict__ Wt, int K, int N) {
  convt_tile(W, Wt, K, N);
}

// fused convt of six DxD matrices (q,k,v,kg,vg,wo) via blockIdx.z
__global__ __launch_bounds__(256) void convt6_kernel(
    const float* __restrict__ W0, const float* __restrict__ W1,
    const float* __restrict__ W2, const float* __restrict__ W3,
    const float* __restrict__ W4, const float* __restrict__ W5,
    u16* __restrict__ out) {
  int z = blockIdx.z;
  const float* W = (z == 0) ? W0 : (z == 1) ? W1 : (z == 2) ? W2
                 : (z == 3) ? W3 : (z == 4) ? W4 : W5;
  convt_tile(W, out + (size_t)z * DMODEL * DMODEL, DMODEL, DMODEL);
}

// concat per-layer biases bq|bk|bv|bkg|bvg -> fb[L][NQKV] (run once)
__global__ __launch_bounds__(256) void bias_cat_kernel(
    const float* __restrict__ bq, const float* __restrict__ bk,
    const float* __restrict__ bv, const float* __restrict__ bkg,
    const float* __restrict__ bvg, float* __restrict__ fb) {
  int idx = blockIdx.x * 256 + threadIdx.x;
  if (idx >= NLAYER * NQKV) return;
  int l = idx / NQKV, j = idx % NQKV;
  float v;
  if (j < 768)       v = bq[l * DMODEL + j];
  else if (j < 1536) v = bk[l * DMODEL + j - 768];
  else if (j < 2304) v = bv[l * DMODEL + j - 1536];
  else if (j < 3072) v = bkg[l * DMODEL + j - 2304];
  else               v = bvg[l * DMODEL + j - 3072];
  fb[idx] = v;
}

// ---------------- bf16 MFMA GEMM (m97 structure): C = A[M,K] @ Bt[N,K]^T + bias ----
// EPI: 0 = bias -> fp32 out; 1 = bias+gelu -> bf16 out;
// EPI: 2 = bias -> bf16 out, with V columns [1536,2304) redirected TRANSPOSED
//          into VtOut[b][h][d][s] (head-transposed V panel for local attention).
template <int EPI>
__global__ __launch_bounds__(256) void mfma_gemm_kernel(
    const u16* __restrict__ A, const u16* __restrict__ Bt,
    const float* __restrict__ bias, float* __restrict__ Cf,
    u16* __restrict__ Cb, u16* __restrict__ VtOut, int M, int N, int K) {
  __shared__ u16 As[128 * 32];
  __shared__ u16 Bs[128 * 32];
  int t = threadIdx.x;
  int lane = t & 63;
  int w = t >> 6;
  int m0 = blockIdx.x * 128, n0 = blockIdx.y * 128;
  int wm = (w >> 1) * 64, wn = (w & 1) * 64;

  f32x4 acc[4][4];
#pragma unroll
  for (int i = 0; i < 4; i++)
#pragma unroll
    for (int j = 0; j < 4; j++) acc[i][j] = (f32x4){0.f, 0.f, 0.f, 0.f};

  int rA = lane >> 2;
  int kseg = (lane & 3) * 8;
  const u16* gA0 = A + (size_t)(m0 + 2 * w * 16 + rA) * K + kseg;
  const u16* gB0 = Bt + (size_t)(n0 + 2 * w * 16 + rA) * K + kseg;
  char* lA0 = (char*)As + (2 * w) * 1024;
  char* lB0 = (char*)Bs + (2 * w) * 1024;

  const u16* fA = As + (wm + (lane & 15)) * 32 + (lane >> 4) * 8;
  const u16* fB = Bs + (wn + (lane & 15)) * 32 + (lane >> 4) * 8;

  for (int k0 = 0; k0 < K; k0 += 32) {
    load_lds16(gA0 + k0, lA0);
    load_lds16(gA0 + (size_t)16 * K + k0, lA0 + 1024);
    load_lds16(gB0 + k0, lB0);
    load_lds16(gB0 + (size_t)16 * K + k0, lB0 + 1024);
    __syncthreads();
    bf16x8 fa[4], fb[4];
#pragma unroll
    for (int i = 0; i < 4; i++) {
      fa[i] = *(const bf16x8*)(fA + i * 16 * 32);
      fb[i] = *(const bf16x8*)(fB + i * 16 * 32);
    }
#pragma unroll
    for (int mi = 0; mi < 4; mi++)
#pragma unroll
      for (int ni = 0; ni < 4; ni++)
        acc[mi][ni] = __builtin_amdgcn_mfma_f32_16x16x32_bf16(
            fa[mi], fb[ni], acc[mi][ni], 0, 0, 0);
    __syncthreads();
  }

  int col0 = n0 + wn + (lane & 15);
  int row0 = m0 + wm + (lane >> 4) * 4;
#pragma unroll
  for (int mi = 0; mi < 4; mi++)
#pragma unroll
    for (int ni = 0; ni < 4; ni++) {
      int ncol = col0 + ni * 16;
      float bvv = bias[ncol];
      if (EPI == 2 && ncol >= 1536 && ncol < 2304) {
        // V head panel, transposed: vT[((bb*12+hh)*64+dd)*2048 + s]
        int dcol = ncol - 1536;
        int h2 = dcol >> 6, dd = dcol & 63;
        int row0m = row0 + mi * 16;
        int bb2 = row0m >> 11, ss = row0m & 2047;
        ushort4 pk;
        pk.x = f2bf(acc[mi][ni][0] + bvv);
        pk.y = f2bf(acc[mi][ni][1] + bvv);
        pk.z = f2bf(acc[mi][ni][2] + bvv);
        pk.w = f2bf(acc[mi][ni][3] + bvv);
        *(ushort4*)(VtOut + (((size_t)(bb2 * NHEAD + h2)) * DHEAD + dd) * SSEQ + ss) = pk;
      } else {
#pragma unroll
        for (int r = 0; r < 4; r++) {
          int mrow = row0 + mi * 16 + r;
          float vv = acc[mi][ni][r] + bvv;
          if (EPI == 0) {
            Cf[(size_t)mrow * N + ncol] = vv;
          } else if (EPI == 1) {
            vv = 0.5f * vv * (1.f + erff(vv * 0.70710678118654752f));
            Cb[(size_t)mrow * N + ncol] = f2bf(vv);
          } else {
            Cb[(size_t)mrow * N + ncol] = f2bf(vv);
          }
        }
      }
    }
}

// ---------------- local (banded) attention, MFMA flash-style ----------------
// Block = 64 queries of one (b,h); 4 waves x 16 q-rows. 9 KV tiles of 64 keys.
// Swapped QK^T (S^T = K @ Q^T) so softmax state is lane-local; PV via
// OT = mfma(V^T, P) with V^T staged from the vT panel the QKV GEMM produced.
// K/V^T rows are 128B -> XOR-swizzle 16B segments via pre-swizzled global src.
// grid = B*H*32 = 1536 (bijective XCD swizzle: 1536 % 8 == 0).
__global__ __launch_bounds__(256) void local_attn_kernel(
    const u16* __restrict__ qkv, const u16* __restrict__ vT,
    const float* __restrict__ amask, u16* __restrict__ Ob) {
  int x = blockIdx.x;
  int lid = (x & 7) * 192 + (x >> 3);      // XCD-contiguous chunks
  int ck = lid & 31;
  int hh = (lid >> 5) % NHEAD;
  int bb = lid / (32 * NHEAD);
  int q0 = ck * 64;

  __shared__ __align__(16) u16 Ks[64 * 64];   // [key][dim], segs ^ (key&7)
  __shared__ __align__(16) u16 Vs[64 * 64];   // [dim][key], segs ^ (dim&7)
  __shared__ __align__(16) u16 Pl[4][16 * 72];
  __shared__ float sm[64];
  __shared__ float k0s[64], v0s[64];

  int t = threadIdx.x;
  int l = t & 63;
  int w = t >> 6;
  int lq = l & 15;   // q (n index)
  int g  = l >> 4;   // 4-lane group

  // one-time: token-0 K and V columns (joint-softmax global key)
  if (t < 128) {
    int d = t & 63;
    if (t < 64) {
      u16 kv = qkv[((size_t)bb * SSEQ) * NQKV + 768 + hh * DHEAD + d];
      k0s[d] = __uint_as_float(((u32)kv) << 16);
    } else {
      u16 vv = vT[(((size_t)(bb * NHEAD + hh)) * DHEAD + d) * SSEQ];
      v0s[d] = __uint_as_float(((u32)vv) << 16);
    }
  }

  // Q B-fragments direct from global (per-lane 16B, held for whole kernel)
  int qtok = q0 + w * 16 + lq;
  const u16* qp = qkv + ((size_t)(bb * SSEQ + qtok)) * NQKV + hh * DHEAD + g * 8;
  bf16x8 qf0 = *(const bf16x8*)(qp);        // dims g*8..+7
  bf16x8 qf1 = *(const bf16x8*)(qp + 32);   // dims 32+g*8..+7

  // staging geometry: inst i covers rows (i*32 + w*8 + (l>>3)), phys seg l&7
  int srow = w * 8 + (l >> 3);
  int lseg = (l & 7) ^ (srow & 7);          // same for srow and srow+32
  const u16* kbase = qkv + ((size_t)bb * SSEQ) * NQKV + 768 + hh * DHEAD + lseg * 8;
  const u16* vbase = vT + (((size_t)(bb * NHEAD + hh)) * DHEAD + srow) * SSEQ + lseg * 8;
  char* ldK0 = (char*)Ks + w * 1024;
  char* ldK1 = (char*)Ks + 4096 + w * 1024;
  char* ldV0 = (char*)Vs + w * 1024;
  char* ldV1 = (char*)Vs + 4096 + w * 1024;

  float mrun = -INFINITY, lrun = 0.f;
  f32x4 ot[4];
#pragma unroll
  for (int ti = 0; ti < 4; ti++) ot[ti] = (f32x4){0.f, 0.f, 0.f, 0.f};

  u16* pw = &Pl[w][0];

  for (int tt = 0; tt < 9; tt++) {
    int jp0 = q0 - 256 + tt * 64;           // 64-aligned, so never partial
    if (jp0 < 0 || jp0 >= SSEQ) continue;

    load_lds16(kbase + (size_t)(jp0 + srow) * NQKV, ldK0);
    load_lds16(kbase + (size_t)(jp0 + srow + 32) * NQKV, ldK1);
    load_lds16(vbase + jp0, ldV0);
    load_lds16(vbase + (size_t)32 * SSEQ + jp0, ldV1);
    if (t < 64) sm[t] = amask[bb * SSEQ + jp0 + t];
    __syncthreads();

    // S^T = K @ Q^T : 4 key-tiles x (K=64 -> 2 mfma)
    f32x4 st[4];
#pragma unroll
    for (int ti = 0; ti < 4; ti++) {
      st[ti] = (f32x4){0.f, 0.f, 0.f, 0.f};
      int krow = ti * 16 + lq;
      const u16* kr = Ks + krow * 64;
      bf16x8 kf0 = *(const bf16x8*)(kr + ((0 + g) ^ (krow & 7)) * 8);
      bf16x8 kf1 = *(const bf16x8*)(kr + ((4 + g) ^ (krow & 7)) * 8);
      st[ti] = __builtin_amdgcn_mfma_f32_16x16x32_bf16(kf0, qf0, st[ti], 0, 0, 0);
      st[ti] = __builtin_amdgcn_mfma_f32_16x16x32_bf16(kf1, qf1, st[ti], 0, 0, 0);
    }

    // mask + online softmax (lane holds q = lq, keys ti*16 + g*4 + r)
    float mx = -INFINITY;
#pragma unroll
    for (int ti = 0; ti < 4; ti++)
#pragma unroll
      for (int r = 0; r < 4; r++) {
        int kk = ti * 16 + g * 4 + r;
        int jp = jp0 + kk;
        int rel = jp - qtok;
        bool ok = (jp != 0) && (rel <= 256) && (rel >= -256) && (sm[kk] > 0.5f);
        float s = ok ? st[ti][r] * QSCALE : NEGV;
        st[ti][r] = s;
        mx = fmaxf(mx, s);
      }
    mx = fmaxf(mx, __shfl_xor(mx, 16, 64));
    mx = fmaxf(mx, __shfl_xor(mx, 32, 64));
    float mnew = fmaxf(mrun, mx);
    float cr = expf(mrun - mnew);
    float ssum = 0.f;
#pragma unroll
    for (int ti = 0; ti < 4; ti++) {
      float e0 = expf(st[ti][0] - mnew);
      float e1 = expf(st[ti][1] - mnew);
      float e2 = expf(st[ti][2] - mnew);
      float e3 = expf(st[ti][3] - mnew);
      ssum += (e0 + e1) + (e2 + e3);
      ushort4 pk;
      pk.x = f2bf(e0); pk.y = f2bf(e1); pk.z = f2bf(e2); pk.w = f2bf(e3);
      *(ushort4*)(pw + lq * 72 + ti * 16 + g * 4) = pk;   // P[q][k], pitch 72
    }
    ssum += __shfl_xor(ssum, 16, 64);
    ssum += __shfl_xor(ssum, 32, 64);
    lrun = lrun * cr + ssum;
    mrun = mnew;

    // rescale running output (per-lane: all ot share this lane's q)
#pragma unroll
    for (int ti = 0; ti < 4; ti++) {
      ot[ti][0] *= cr; ot[ti][1] *= cr; ot[ti][2] *= cr; ot[ti][3] *= cr;
    }

    // OT += V^T @ P^T : A = Vs[d][k] (4 d-tiles), B = P[q][k]
    bf16x8 pf0 = *(const bf16x8*)(pw + lq * 72 + g * 8);
    bf16x8 pf1 = *(const bf16x8*)(pw + lq * 72 + 32 + g * 8);
#pragma unroll
    for (int ti = 0; ti < 4; ti++) {
      int drow = ti * 16 + lq;
      const u16* vr = Vs + drow * 64;
      bf16x8 vf0 = *(const bf16x8*)(vr + ((0 + g) ^ (drow & 7)) * 8);
      bf16x8 vf1 = *(const bf16x8*)(vr + ((4 + g) ^ (drow & 7)) * 8);
      ot[ti] = __builtin_amdgcn_mfma_f32_16x16x32_bf16(vf0, pf0, ot[ti], 0, 0, 0);
      ot[ti] = __builtin_amdgcn_mfma_f32_16x16x32_bf16(vf1, pf1, ot[ti], 0, 0, 0);
    }
    __syncthreads();
  }

  // token-0 global key column (joint softmax, never masked)
  float gs = 0.f;
#pragma unroll
  for (int j = 0; j < 8; j++) {
    gs = fmaf(bf2f(qf0[j]), k0s[g * 8 + j], gs);
    gs = fmaf(bf2f(qf1[j]), k0s[32 + g * 8 + j], gs);
  }
  gs += __shfl_xor(gs, 16, 64);
  gs += __shfl_xor(gs, 32, 64);
  float gsc = gs * QSCALE;
  float mnew = fmaxf(mrun, gsc);
  float cr = expf(mrun - mnew);
  float p0 = expf(gsc - mnew);
  float linv = 1.0f / (lrun * cr + p0);

  // finalize -> per-wave LDS stage (reuse Pl) -> coalesced bf16 store
#pragma unroll
  for (int ti = 0; ti < 4; ti++) {
    int d = ti * 16 + g * 4;
    ushort4 ov;
    ov.x = f2bf((ot[ti][0] * cr + p0 * v0s[d + 0]) * linv);
    ov.y = f2bf((ot[ti][1] * cr + p0 * v0s[d + 1]) * linv);
    ov.z = f2bf((ot[ti][2] * cr + p0 * v0s[d + 2]) * linv);
    ov.w = f2bf((ot[ti][3] * cr + p0 * v0s[d + 3]) * linv);
    *(ushort4*)(pw + lq * 72 + d) = ov;
  }
  int qq = l >> 2, s4 = l & 3;
  uint4 o0 = *(const uint4*)(pw + qq * 72 + s4 * 8);
  uint4 o1 = *(const uint4*)(pw + qq * 72 + 32 + s4 * 8);
  size_t ob = ((size_t)(bb * SSEQ + q0 + w * 16 + qq)) * DMODEL + hh * DHEAD + s4 * 8;
  *(uint4*)(Ob + ob) = o0;
  *(uint4*)(Ob + ob + 32) = o1;
}

// ---------------- global token-0 query attention, fused qg projection ----------
// Block = one (b,h). First computes qv[64] = QSCALE*(h[b,0,:] @ Wg[:,h*64+d] + bg)
// via LDS-staged x + 4-way split-K (removes the 288us rowvec dispatch), then the
// full-sequence softmax over kg/vg as before. grid = B*H = 48.
__global__ __launch_bounds__(256) void global_attn_kernel(
    const float* __restrict__ h, const float* __restrict__ Wg,
    const float* __restrict__ bg, const u16* __restrict__ qkv,
    const float* __restrict__ amask, u16* __restrict__ Ob) {
  int bb = blockIdx.x / NHEAD;
  int hh = blockIdx.x % NHEAD;
  __shared__ float p[SSEQ];
  __shared__ float h0[DMODEL];
  __shared__ float qv[64];
  __shared__ float red[256];
  __shared__ float part[4][64];
  int t = threadIdx.x;

  // stage h[b, token 0, :]
#pragma unroll
  for (int i = 0; i < 3; i++) h0[t + i * 256] = h[(size_t)bb * SSEQ * DMODEL + t + i * 256];
  __syncthreads();

  // qg projection: d = t&63, 4 K-stripes of 192; weight reads 256B/wave coalesced
  {
    int d = t & 63, stripe = t >> 6;
    float acc = 0.f;
    int k0 = stripe * 192;
#pragma unroll 4
    for (int kk = k0; kk < k0 + 192; kk++)
      acc = fmaf(h0[kk], Wg[(size_t)kk * DMODEL + hh * DHEAD + d], acc);
    part[stripe][d] = acc;
  }
  __syncthreads();
  if (t < 64)
    qv[t] = (part[0][t] + part[1][t] + part[2][t] + part[3][t] + bg[hh * DHEAD + t]) * QSCALE;
  __syncthreads();

  float mx = -INFINITY;
#pragma unroll
  for (int i = 0; i < 8; i++) {
    int s = t + i * 256;
    const u16* kp = qkv + ((size_t)(bb * SSEQ + s)) * NQKV + 2304 + hh * DHEAD;
    float acc = 0.f;
#pragma unroll
    for (int d8 = 0; d8 < 8; d8++) {
      float f8[8];
      unpack8(*(const uint4*)(kp + d8 * 8), f8);
#pragma unroll
      for (int u = 0; u < 8; u++) acc = fmaf(qv[d8 * 8 + u], f8[u], acc);
    }
    if (!(amask[bb * SSEQ + s] > 0.5f)) acc = NEGV;
    p[s] = acc;
    mx = fmaxf(mx, acc);
  }
  red[t] = mx;
  __syncthreads();
  for (int sft = 128; sft > 0; sft >>= 1) {
    if (t < sft) red[t] = fmaxf(red[t], red[t + sft]);
    __syncthreads();
  }
  mx = red[0];
  __syncthreads();
  float lsum = 0.f;
#pragma unroll
  for (int i = 0; i < 8; i++) {
    int s = t + i * 256;
    float e = expf(p[s] - mx);
    p[s] = e;
    lsum += e;
  }
  float l = block_sum_256(lsum, red);
  int d = t & 63, stripe = t >> 6;
  float acc = 0.f;
  for (int s = stripe * 512; s < stripe * 512 + 512; s++) {
    u16 vv = qkv[((size_t)(bb * SSEQ + s)) * NQKV + 3072 + hh * DHEAD + d];
    acc = fmaf(p[s], __uint_as_float(((u32)vv) << 16), acc);
  }
  part[stripe][d] = acc;
  __syncthreads();
  if (t < 64) {
    float sum = part[0][t] + part[1][t] + part[2][t] + part[3][t];
    Ob[((size_t)(bb * SSEQ)) * DMODEL + hh * DHEAD + t] = f2bf(sum / l);
  }
}

// ---------------- split-K GEMV + tanh (pooler): y[b,j] = tanh(x[b,:]@W[:,j]+b) --
// grid = B * N/64 blocks; 256 threads = 64 cols x 4 K-stripes; LDS-staged x.
__global__ __launch_bounds__(256) void gemv_tanh_kernel(
    const float* __restrict__ x, size_t xstride, const float* __restrict__ Wt,
    const float* __restrict__ bias, float* __restrict__ y, int K, int N) {
  __shared__ float xs[DMODEL];
  __shared__ float part[4][64];
  int ncg = N >> 6;
  int bb = blockIdx.x / ncg;
  int cg = blockIdx.x % ncg;
  int t = threadIdx.x;
  const float* xr = x + (size_t)bb * xstride;
  for (int i = t; i < K; i += 256) xs[i] = xr[i];
  __syncthreads();
  int j = cg * 64 + (t & 63);
  int stripe = t >> 6;
  int kq = K >> 2;
  int k0 = stripe * kq;
  float acc = 0.f;
#pragma unroll 4
  for (int kk = k0; kk < k0 + kq; kk++)
    acc = fmaf(xs[kk], Wt[(size_t)kk * N + j], acc);
  part[stripe][t & 63] = acc;
  __syncthreads();
  if (t < 64) {
    int jj = cg * 64 + t;
    float s = part[0][t] + part[1][t] + part[2][t] + part[3][t] + bias[jj];
    y[(size_t)bb * N + jj] = tanhf(s);
  }
}

// ---------------- final head ----------------
__global__ __launch_bounds__(256) void head_kernel(
    const float* __restrict__ pooled, const float* __restrict__ clsW,
    const float* __restrict__ clsb, const float* __restrict__ mcW,
    const float* __restrict__ mcb, float* __restrict__ out) {
  __shared__ float lg[8];
  __shared__ float o16[16];
  int t = threadIdx.x;
  if (t < 8) {
    int bb = t >> 1, cc2 = t & 1;
    float acc = clsb[cc2];
    for (int kk = 0; kk < DMODEL; kk++)
      acc = fmaf(pooled[bb * DMODEL + kk], clsW[kk * 2 + cc2], acc);
    lg[t] = acc;
  }
  __syncthreads();
  if (t < 16) {
    float acc = mcb[t];
    for (int i = 0; i < 8; i++) acc = fmaf(lg[i], mcW[i * 16 + t], acc);
    o16[t] = acc;
  }
  __syncthreads();
  if (t == 0) {
    float mx = o16[0];
    for (int i = 1; i < 16; i++) mx = fmaxf(mx, o16[i]);
    float sum = 0.f;
    float e[16];
    for (int i = 0; i < 16; i++) { e[i] = expf(o16[i] - mx); sum += e[i]; }
    for (int i = 0; i < 16; i++) out[i] = e[i] / sum;
  }
}

// ---------------- host launcher ----------------
extern "C" void kernel_launch(void* const* d_in, const int* in_sizes, int n_in,
                              void* d_out, int out_size, void* d_ws, size_t ws_size,
                              hipStream_t stream) {
  (void)in_sizes; (void)n_in; (void)out_size; (void)ws_size;
  const int*   ids      = (const int*)d_in[0];
  const float* amask    = (const float*)d_in[1];
  const float* emb_word = (const float*)d_in[2];
  const float* emb_pos  = (const float*)d_in[3];
  const float* ln_emb_s = (const float*)d_in[4];
  const float* ln_emb_b = (const float*)d_in[5];
  const float* Wq  = (const float*)d_in[6];
  const float* Wk  = (const float*)d_in[7];
  const float* Wv  = (const float*)d_in[8];
  const float* Wqg = (const float*)d_in[9];
  const float* Wkg = (const float*)d_in[10];
  const float* Wvg = (const float*)d_in[11];
  const float* Wo  = (const float*)d_in[12];
  const float* bq  = (const float*)d_in[13];
  const float* bk  = (const float*)d_in[14];
  const float* bv  = (const float*)d_in[15];
  const float* bqg = (const float*)d_in[16];
  const float* bkg = (const float*)d_in[17];
  const float* bvg = (const float*)d_in[18];
  const float* bo  = (const float*)d_in[19];
  const float* ln1_s = (const float*)d_in[20];
  const float* ln1_b = (const float*)d_in[21];
  const float* Wi  = (const float*)d_in[22];
  const float* bi  = (const float*)d_in[23];
  const float* Wf  = (const float*)d_in[24];
  const float* bf_ = (const float*)d_in[25];
  const float* ln2_s = (const float*)d_in[26];
  const float* ln2_b = (const float*)d_in[27];
  const float* pooler_W = (const float*)d_in[28];
  const float* pooler_b = (const float*)d_in[29];
  const float* cls_W = (const float*)d_in[30];
  const float* cls_b = (const float*)d_in[31];
  const float* mc_W  = (const float*)d_in[32];
  const float* mc_b  = (const float*)d_in[33];
  float* out = (float*)d_out;

  float* ws = (float*)d_ws;
  const size_t NT = (size_t)BBATCH * SSEQ;     // 8192 tokens
  const size_t TD = NT * DMODEL;               // 6.29M
  const size_t WDD = (size_t)DMODEL * DMODEL;  // 589824

  float* h  = ws;                    // [NT, D] fp32
  float* Pc = ws + TD;               // fp32 GEMM-out panel
  u16*  ub  = (u16*)(ws + 2 * TD);
  u16* hb   = ub;                    // [NT, D] bf16
  u16* attb = ub + TD;               // [NT, D] bf16
  u16* qkvb = ub + 2 * TD;           // [NT, NQKV] bf16  (5*TD)
  u16* midb = ub + 7 * TD;           // [NT, DFF] bf16   (4*TD)
  u16* vt   = midb;                  // [B,H,64,S] bf16 V^T panel (aliases midb:
                                     //  live QKV-GEMM..local_attn, dead by FFN1)
  u16* wt   = ub + 11 * TD;          // per-layer weights: 14*WDD u16
  u16* wqkvT = wt;                   // [NQKV, D]
  u16* woT   = wt + 5 * WDD;         // [D, D]
  u16* wiT   = wt + 6 * WDD;         // [DFF, D] (4 WDD)
  u16* wfT   = wt + 10 * WDD;        // [D, DFF] (4 WDD)
  float* fbias  = (float*)(wt + 14 * WDD);       // [L, NQKV]
  float* pooled = fbias + NLAYER * NQKV;         // [B, D]

  embed_ln_kernel<<<(int)NT, 256, 0, stream>>>(ids, emb_word, emb_pos,
                                               ln_emb_s, ln_emb_b, h, hb);
  bias_cat_kernel<<<(NLAYER * NQKV + 255) / 256, 256, 0, stream>>>(bq, bk, bv, bkg, bvg, fbias);

  dim3 gQKV(NT / 128, NQKV / 128);     // (64, 30)
  dim3 gDD(NT / 128, DMODEL / 128);    // (64, 6)
  dim3 gF1(NT / 128, DFFN / 128);      // (64, 24)
  dim3 c6(DMODEL / 64, DMODEL / 64, 6);
  dim3 cWi(DMODEL / 64, DFFN / 64);    // (12, 48)
  dim3 cWf(DFFN / 64, DMODEL / 64);    // (48, 12)

  for (int l = 0; l < NLAYER; l++) {
    const size_t wd = (size_t)l * WDD;
    convt6_kernel<<<c6, 256, 0, stream>>>(Wq + wd, Wk + wd, Wv + wd,
                                          Wkg + wd, Wvg + wd, Wo + wd, wt);
    convt_kernel<<<cWi, 256, 0, stream>>>(Wi + (size_t)l * DMODEL * DFFN, wiT, DMODEL, DFFN);
    convt_kernel<<<cWf, 256, 0, stream>>>(Wf + (size_t)l * DMODEL * DFFN, wfT, DFFN, DMODEL);

    // fused q|k|v|kg|vg projection -> bf16 panel (+ head-transposed V panel)
    mfma_gemm_kernel<2><<<gQKV, 256, 0, stream>>>(hb, wqkvT, fbias + (size_t)l * NQKV,
                                                  (float*)nullptr, qkvb, vt,
                                                  (int)NT, NQKV, DMODEL);
    local_attn_kernel<<<BBATCH * NHEAD * 32, 256, 0, stream>>>(qkvb, vt, amask, attb);
    global_attn_kernel<<<BBATCH * NHEAD, 256, 0, stream>>>(h, Wqg + wd, bqg + l * DMODEL,
                                                           qkvb, amask, attb);
    // output projection + residual LN
    mfma_gemm_kernel<0><<<gDD, 256, 0, stream>>>(attb, woT, bo + l * DMODEL, Pc,
                                                 (u16*)nullptr, (u16*)nullptr,
                                                 (int)NT, DMODEL, DMODEL);
    add_ln_kernel<<<(int)NT, 256, 0, stream>>>(h, Pc, ln1_s + l * DMODEL, ln1_b + l * DMODEL, hb);
    // FFN
    mfma_gemm_kernel<1><<<gF1, 256, 0, stream>>>(hb, wiT, bi + l * DFFN,
                                                 (float*)nullptr, midb, (u16*)nullptr,
                                                 (int)NT, DFFN, DMODEL);
    mfma_gemm_kernel<0><<<gDD, 256, 0, stream>>>(midb, wfT, bf_ + l * DMODEL, Pc,
                                                 (u16*)nullptr, (u16*)nullptr,
                                                 (int)NT, DMODEL, DFFN);
    add_ln_kernel<<<(int)NT, 256, 0, stream>>>(h, Pc, ln2_s + l * DMODEL, ln2_b + l * DMODEL, hb);
  }

  gemv_tanh_kernel<<<BBATCH * (DMODEL / 64), 256, 0, stream>>>(
      h, (size_t)SSEQ * DMODEL, pooler_W, pooler_b, pooled, DMODEL, DMODEL);
  head_kernel<<<1, 256, 0, stream>>>(pooled, cls_W, cls_b, mc_W, mc_b, out);
}